// Round 16
// baseline (231.657 us; speedup 1.0000x reference)
//
#include <hip/hip_runtime.h>
#include <math.h>

typedef unsigned int u32;
typedef unsigned short u16;
typedef __attribute__((ext_vector_type(8))) short bf16x8;   // 8 bf16 in 4 VGPRs
typedef __attribute__((ext_vector_type(4))) float f32x4;

#define GLOBAL_AS __attribute__((address_space(1)))
#define LDS_AS __attribute__((address_space(3)))

__device__ __forceinline__ void gload_lds16(const void* g, void* s) {
    __builtin_amdgcn_global_load_lds((const GLOBAL_AS void*)g, (LDS_AS void*)s, 16, 0, 0);
}

__device__ inline u16 f2bf(float x) {  // round-to-nearest-even
    union { float f; u32 u; } v; v.f = x;
    u32 r = v.u + 0x7FFFu + ((v.u >> 16) & 1u);
    return (u16)(r >> 16);
}
__device__ inline float bf2f(u16 x) { return __uint_as_float((u32)x << 16); }
__device__ inline float bf_lo(u32 u) { return __uint_as_float(u << 16); }
__device__ inline float bf_hi(u32 u) { return __uint_as_float(u & 0xffff0000u); }

// Clifford sign/slot closed forms:  s = ob ^ ib ;
//   g = -1 iff (ob != 3 && ib == (3 ^ (ob & 1)))
__device__ __forceinline__ int cs_s(int ob, int ib) { return ob ^ ib; }
__device__ __forceinline__ float cs_g(int ob, int ib) {
    return ((ob != 3) && (ib == (3 ^ (ob & 1)))) ? -1.f : 1.f;
}

// ---------------------------------------------------------------------------
// Clifford GNN message passing, fully linearized:
//   agg[n] = sum_e w_e*(h[src] .* r[rel]),  w_e = gate(rel)*norm(e)
//   out    = (Ku.Km).agg + Ku.h + ws*(Ku.msg_b) + upd_b
// Round-15: fused prep kernels now INTERLEAVE roles across blockIdx (even =
// latency/atomic blocks, odd = streaming blocks) so every scheduler round
// holds both: the BW stream saturates HBM while atomic chains hide inside.
// (Round-14 put all fill blocks first -> zero overlap, prepB = sum of parts.)
// Pipeline: memset -> prepA{degree || kbuild|gate} -> alloc ->
//           prepB{fill || tobf_h|tobf_rel} -> agg -> gemm
// ---------------------------------------------------------------------------

// prepA: even blocks -> degree atomics (idx<nbDeg); odd -> kbuild row (idx<256)
// then gate (next nbGate). Grid = 2*max(nbDeg, 256+nbGate).
__global__ __launch_bounds__(256) void prepA_kernel(
    const float* __restrict__ msg_w, const float* __restrict__ upd_w,
    const float* __restrict__ upd_b, const float* __restrict__ msg_b,
    const float* __restrict__ rel_emb, const float* __restrict__ gate_w,
    const float* __restrict__ gate_b, const int* __restrict__ ei, int E,
    u32* __restrict__ deg_src, u32* __restrict__ deg_dst,
    float* __restrict__ gate, u16* __restrict__ Kcomb,
    float* __restrict__ c0, float* __restrict__ c1,
    int R, int nbDeg, int nbGate) {
    __shared__ __align__(16) u16 ms[16384];   // msg_w as bf16, 32KB
    __shared__ float U_s[256];
    __shared__ float wred[4];
    int tid = threadIdx.x;
    int idx = blockIdx.x >> 1;

    if (blockIdx.x & 1) {
        if (idx < 256) {
            // ---- kbuild: Kcomb row p (fragment-packed, 8 replicas) ----
            int p = idx;
            int j = (p & 3) * 64 + (p >> 2);
#pragma unroll
            for (int i = 0; i < 8; ++i) {
                int c8 = i * 256 + tid;
                const float* p8 = msg_w + (size_t)c8 * 8;
                float4 a = *(const float4*)(p8);
                float4 bb = *(const float4*)(p8 + 4);
                u16 tmp[8] = {f2bf(a.x), f2bf(a.y), f2bf(a.z), f2bf(a.w),
                              f2bf(bb.x), f2bf(bb.y), f2bf(bb.z), f2bf(bb.w)};
                *(uint4*)&ms[c8 * 8] = *(const uint4*)tmp;
            }
            int ib = tid >> 6, ic = tid & 63;
            {
                int obu = j >> 6;
                U_s[tid] = cs_g(obu, ib) * upd_w[cs_s(obu, ib) * 4096 + (j & 63) * 64 + ic];
            }
            __syncthreads();
            float acc = 0.f;
#pragma unroll
            for (int ob = 0; ob < 4; ++ob) {
                int s = cs_s(ob, ib);
                float gg = cs_g(ob, ib);
                const u16* mp = ms + s * 4096 + ic;
                const float* us = U_s + ob * 64;
                float a0 = 0.f;
#pragma unroll 8
                for (int oc = 0; oc < 64; ++oc) a0 += us[oc] * bf2f(mp[oc * 64]);
                acc += gg * a0;
            }
            u16 vA = f2bf(acc);          // element (p, k=tid)
            u16 vU = f2bf(U_s[tid]);     // element (p, k=tid+256)
            int pt = p >> 4, pl = p & 15;
            int kgA = (tid >> 3) & 3, elA = tid & 7;
            size_t addrA = (size_t)(pt * 16 + (tid >> 5)) * 512 + (kgA * 16 + pl) * 8 + elA;
            int ku = tid + 256;
            size_t addrU = (size_t)(pt * 16 + (ku >> 5)) * 512 + (kgA * 16 + pl) * 8 + elA;
#pragma unroll
            for (int r = 0; r < 8; ++r) {        // 8 replicas (one per XCD's L2)
                Kcomb[(size_t)r * 131072 + addrA] = vA;
                Kcomb[(size_t)r * 131072 + addrU] = vU;
            }
            float part = U_s[tid] * msg_b[tid];
            int lane = tid & 63, wv = tid >> 6;
#pragma unroll
            for (int d = 32; d > 0; d >>= 1) part += __shfl_down(part, d);
            if (lane == 0) wred[wv] = part;
            __syncthreads();
            if (tid == 0) { c1[p] = wred[0] + wred[1] + wred[2] + wred[3]; c0[p] = upd_b[j]; }
            return;
        }
        int gb = idx - 256;
        if (gb < nbGate) {
            int wv = tid >> 6, lane = tid & 63;
            int r = gb * 4 + wv;
            if (r >= R) return;
            float4 rv = *(const float4*)(rel_emb + (size_t)r * 256 + lane * 4);
            float s = 0.f;
            float rvv[4] = {rv.x, rv.y, rv.z, rv.w};
#pragma unroll
            for (int c = 0; c < 4; ++c) {
                int jj = lane * 4 + c;
                s += rvv[c] * gate_w[(jj & 63) * 4 + (jj >> 6)];
            }
#pragma unroll
            for (int d = 32; d > 0; d >>= 1) s += __shfl_down(s, d);
            if (lane == 0) gate[r] = 1.0f / (1.0f + expf(-(s + gate_b[0])));
        }
        return;
    }
    // even: degree atomics
    if (idx < nbDeg) {
        int e = idx * 256 + tid;
        if (e < E) {
            atomicAdd(&deg_src[ei[e]], 1u);
            atomicAdd(&deg_dst[ei[E + e]], 1u);
        }
    }
}

// Parallel bucket allocator (order irrelevant, only disjointness matters).
__global__ void alloc_kernel(const u32* __restrict__ deg, u32* __restrict__ offs,
                             u32* __restrict__ cursor, u32* __restrict__ total, int N) {
    __shared__ u32 wt[4];
    __shared__ u32 bbase;
    int tid = threadIdx.x, lane = tid & 63, wv = tid >> 6;
    int i = blockIdx.x * 256 + tid;
    u32 d = (i < N) ? deg[i] : 0u;
    u32 sc = d;
#pragma unroll
    for (int s = 1; s < 64; s <<= 1) { u32 o = __shfl_up(sc, s); if (lane >= s) sc += o; }
    if (lane == 63) wt[wv] = sc;
    __syncthreads();
    if (tid == 0) bbase = atomicAdd(total, wt[0] + wt[1] + wt[2] + wt[3]);
    __syncthreads();
    u32 wpre = 0;
    for (int w = 0; w < wv; ++w) wpre += wt[w];
    u32 off = bbase + wpre + sc - d;
    if (i < N) { offs[i] = off; cursor[i] = off; }
}

// prepB: even blocks -> fill (idx<nbFill); odd -> h-stream (idx<nbH,
// grid-stride) then rel-stream. Grid = 2*max(nbFill, nbH+nbRel).
template <int BF>
__global__ __launch_bounds__(256) void prepB_kernel(
    const int* __restrict__ ei, const int* __restrict__ et,
    const u32* __restrict__ deg_src, const u32* __restrict__ deg_dst,
    const float* __restrict__ gate, u32* __restrict__ cursor,
    uint2* __restrict__ edata,
    const float* __restrict__ h, const float* __restrict__ rel_emb,
    u16* __restrict__ h_bf, u16* __restrict__ rel_bf,
    int E, int N, int R, int nbFill, int nbH, int nbRel) {
    int tid = threadIdx.x;
    int idx = blockIdx.x >> 1;
    if (blockIdx.x & 1) {
        if (BF && idx < nbH) {
            int n8 = N * 32;
            for (int i = idx * 256 + tid; i < n8; i += nbH * 256) {
                const float* p8 = h + (size_t)i * 8;
                float4 a = *(const float4*)(p8);
                float4 bb = *(const float4*)(p8 + 4);
                u16 tmp[8] = {f2bf(a.x), f2bf(a.y), f2bf(a.z), f2bf(a.w),
                              f2bf(bb.x), f2bf(bb.y), f2bf(bb.z), f2bf(bb.w)};
                *(uint4*)(h_bf + (size_t)i * 8) = *(const uint4*)tmp;
            }
            return;
        }
        int rb = idx - (BF ? nbH : 0);
        if (BF && rb < nbRel) {
            int i = rb * 256 + tid;
            if (i < R * 32) {
                const float* p8 = rel_emb + (size_t)i * 8;
                float4 a = *(const float4*)(p8);
                float4 bb = *(const float4*)(p8 + 4);
                u16 tmp[8] = {f2bf(a.x), f2bf(a.y), f2bf(a.z), f2bf(a.w),
                              f2bf(bb.x), f2bf(bb.y), f2bf(bb.z), f2bf(bb.w)};
                *(uint4*)(rel_bf + (size_t)i * 8) = *(const uint4*)tmp;
            }
        }
        return;
    }
    // even: bucket-fill
    if (idx < nbFill) {
        int e = idx * 256 + tid;
        if (e < E) {
            int src = ei[e];
            int dst = ei[E + e];
            int rel = et[e];
            float w = gate[rel] *
                      rsqrtf(fmaxf((float)deg_src[src] * (float)deg_dst[dst], 1.0f));
            u32 pos = atomicAdd(&cursor[dst], 1u);
            edata[pos] = make_uint2((u32)src | ((u32)rel << 18), __float_as_uint(w));
        }
    }
}

// 2 nodes per wave (lanes 0-31 = node A, 32-63 = node B; 16B/lane).
// Predicated x4-unrolled edge loop: tail edges use clamped index (cache-hit
// duplicate) with zero weight. Every lane accumulates the full per-node wsum;
// lane l32==0 writes it directly (no cross-lane reduction).
template <int BF>
__global__ __launch_bounds__(256) void agg_kernel(
    const float* __restrict__ h, const u16* __restrict__ h_bf,
    const float* __restrict__ rel_emb, const u16* __restrict__ rel_bf,
    const u32* __restrict__ offs, const u32* __restrict__ deg_dst,
    const uint2* __restrict__ edata,
    u16* __restrict__ agg_bf, float* __restrict__ wsum_arr, int N) {
    int wv = threadIdx.x >> 6, lane = threadIdx.x & 63;
    int half = lane >> 5, l32 = lane & 31;
    int n = (blockIdx.x * 4 + wv) * 2 + half;
    bool valid = n < N;
    u32 off = valid ? offs[n] : 0u;
    u32 dd  = valid ? deg_dst[n] : 0u;
    float acc[8];
#pragma unroll
    for (int j = 0; j < 8; ++j) acc[j] = 0.f;
    float wsum = 0.f;

    for (u32 e = 0; e < dd; e += 4) {
        uint2 d[4];
        uint4 hv[4], rv[4];
        float wq[4];
#pragma unroll
        for (int q = 0; q < 4; ++q) {
            u32 idx = e + q;
            u32 cl = (idx < dd) ? idx : (dd - 1);   // clamp -> dup line, cache hit
            d[q] = edata[off + cl];
            wq[q] = (idx < dd) ? __uint_as_float(d[q].y) : 0.f;
        }
#pragma unroll
        for (int q = 0; q < 4; ++q) {
            u32 src = d[q].x & 0x3FFFFu, rel = d[q].x >> 18;
            if (BF) {
                hv[q] = *(const uint4*)(h_bf + (size_t)src * 256 + l32 * 8);
                rv[q] = *(const uint4*)(rel_bf + (size_t)rel * 256 + l32 * 8);
            } else {
                const float* hp = h + (size_t)src * 256 + l32 * 8;
                const float* rp = rel_emb + (size_t)rel * 256 + l32 * 8;
                float4 hf0 = *(const float4*)hp, hf1 = *(const float4*)(hp + 4);
                float4 rf0 = *(const float4*)rp, rf1 = *(const float4*)(rp + 4);
                u16 th[8] = {f2bf(hf0.x), f2bf(hf0.y), f2bf(hf0.z), f2bf(hf0.w),
                             f2bf(hf1.x), f2bf(hf1.y), f2bf(hf1.z), f2bf(hf1.w)};
                u16 tr[8] = {f2bf(rf0.x), f2bf(rf0.y), f2bf(rf0.z), f2bf(rf0.w),
                             f2bf(rf1.x), f2bf(rf1.y), f2bf(rf1.z), f2bf(rf1.w)};
                hv[q] = *(const uint4*)th;
                rv[q] = *(const uint4*)tr;
            }
        }
#pragma unroll
        for (int q = 0; q < 4; ++q) {
            float w = wq[q];
            u32 hu[4] = {hv[q].x, hv[q].y, hv[q].z, hv[q].w};
            u32 ru[4] = {rv[q].x, rv[q].y, rv[q].z, rv[q].w};
#pragma unroll
            for (int c = 0; c < 4; ++c) {
                acc[c * 2 + 0] += w * bf_lo(hu[c]) * bf_lo(ru[c]);
                acc[c * 2 + 1] += w * bf_hi(hu[c]) * bf_hi(ru[c]);
            }
            wsum += w;
        }
    }

    if (valid) {
        u32 outw[4];
#pragma unroll
        for (int c = 0; c < 4; ++c)
            outw[c] = (u32)f2bf(acc[c * 2]) | ((u32)f2bf(acc[c * 2 + 1]) << 16);
        *(uint4*)(agg_bf + (size_t)n * 512 + l32 * 8) = *(const uint4*)outw;
        if (l32 == 0) wsum_arr[n] = wsum;   // already the full sum per lane
    }
}

// LDS-staged K=512 GEMM. Block = 32 rows x 256 cols; 4 waves, each 32x64.
// x=[agg|h] staged async into swizzled LDS via global_load_lds (dest linear,
// per-lane SOURCE pre-swizzled). B = fragment-packed Kcomb (1KB coalesced
// bursts) from the XCD-local replica.
// out[row][p] = acc + c0[p] + c1[p]*wsum[row].
__global__ __launch_bounds__(256, 4) void gemm_lds_kernel(
    float* __restrict__ dio, const u16* __restrict__ agg_bf,
    const u16* __restrict__ Kcomb, const u16* __restrict__ h_bf,
    const float* __restrict__ wsum_arr,
    const float* __restrict__ c0, const float* __restrict__ c1, int N) {
    __shared__ __align__(16) u16 xs[32 * 512];   // 32 KiB
    const int lane = threadIdx.x & 63;
    const int wv = threadIdx.x >> 6;      // wave owns output cols [wv*64, +64)
    const int l15 = lane & 15;
    const int kg = lane >> 4;             // k-group 0..3
    const int m0 = blockIdx.x * 32;
    const int pbase = wv * 64;
    const int pt0 = wv * 4;               // first B fragment-tile index
    const u16* Kr = Kcomb + (size_t)(blockIdx.x & 7) * 131072;  // XCD replica

    // ---- async stage x=[agg|h] rows -> swizzled LDS (1 row / issue) ----
    {
        int j0 = lane * 8;                       // dest u16 offset in row
#pragma unroll
        for (int i = 0; i < 8; ++i) {
            int m = i * 4 + wv;                  // 0..31
            int row = m0 + m;
            if (row >= N) row = N - 1;           // clamp; masked at store
            int ks = j0 ^ ((m & 7) << 3);        // pre-swizzled source k
            const u16* src = (j0 < 256)
                ? agg_bf + (size_t)row * 512 + ks
                : h_bf + (size_t)row * 256 + (ks - 256);
            gload_lds16(src, &xs[m * 512]);
        }
    }
    __syncthreads();   // drains global_load_lds; also fences in-place d_out use

    f32x4 acc[2][4];
#pragma unroll
    for (int f = 0; f < 2; ++f)
#pragma unroll
        for (int nf = 0; nf < 4; ++nf) acc[f][nf] = (f32x4)(0.f);

    const int swz = (l15 & 7) << 3;
#pragma unroll 4
    for (int k0 = 0; k0 < 512; k0 += 32) {
        int kk = k0 + kg * 8;
        int ksi = k0 >> 5;
        bf16x8 a[2], b[4];
#pragma unroll
        for (int f = 0; f < 2; ++f)
            a[f] = *(const bf16x8*)&xs[(f * 16 + l15) * 512 + (kk ^ swz)];
#pragma unroll
        for (int nf = 0; nf < 4; ++nf)
            b[nf] = *(const bf16x8*)(Kr + (size_t)((pt0 + nf) * 16 + ksi) * 512 + lane * 8);
#pragma unroll
        for (int f = 0; f < 2; ++f)
#pragma unroll
            for (int nf = 0; nf < 4; ++nf)
                acc[f][nf] = __builtin_amdgcn_mfma_f32_16x16x32_bf16(a[f], b[nf], acc[f][nf], 0, 0, 0);
    }

    // ---- epilogue: y = acc + c0[p] + c1[p]*wsum[row] ----
    float b0[4], b1[4];
#pragma unroll
    for (int nf = 0; nf < 4; ++nf) {
        int p = pbase + nf * 16 + l15;
        b0[nf] = c0[p];
        b1[nf] = c1[p];
    }
#pragma unroll
    for (int f = 0; f < 2; ++f) {
#pragma unroll
        for (int r = 0; r < 4; ++r) {
            int row = m0 + f * 16 + kg * 4 + r;
            if (row >= N) continue;
            float wsv = wsum_arr[row];
#pragma unroll
            for (int nf = 0; nf < 4; ++nf) {
                int p = pbase + nf * 16 + l15;
                dio[(size_t)row * 256 + p] = acc[f][nf][r] + b0[nf] + b1[nf] * wsv;
            }
        }
    }
}

// Fallback (no bf16 workspace): register GEMM, packed-B, barrier before epilogue.
__global__ __launch_bounds__(256, 4) void gemm_reg_kernel(
    float* __restrict__ dio, const u16* __restrict__ agg_bf,
    const u16* __restrict__ Kcomb,
    const float* __restrict__ h,
    const float* __restrict__ wsum_arr,
    const float* __restrict__ c0, const float* __restrict__ c1, int N) {
    const int lane = threadIdx.x & 63;
    const int wv = threadIdx.x >> 6;
    const int l15 = lane & 15;
    const int kg = lane >> 4;
    const int m0 = blockIdx.x * 32;
    const int pbase = wv * 64;
    const int pt0 = wv * 4;

    f32x4 acc[2][4];
#pragma unroll
    for (int f = 0; f < 2; ++f)
#pragma unroll
        for (int nf = 0; nf < 4; ++nf) acc[f][nf] = (f32x4)(0.f);

    int rowA[2];
#pragma unroll
    for (int f = 0; f < 2; ++f) {
        int r = m0 + f * 16 + l15;
        rowA[f] = (r < N) ? r : (N - 1);
    }
    const u16* Kr = Kcomb + (size_t)(blockIdx.x & 7) * 131072;

#pragma unroll 2
    for (int k0 = 0; k0 < 256; k0 += 32) {
        int kk = k0 + kg * 8;
        int ksi = k0 >> 5;
        bf16x8 a[2], b[4];
#pragma unroll
        for (int f = 0; f < 2; ++f)
            a[f] = *(const bf16x8*)(agg_bf + (size_t)rowA[f] * 512 + kk);
#pragma unroll
        for (int nf = 0; nf < 4; ++nf)
            b[nf] = *(const bf16x8*)(Kr + (size_t)((pt0 + nf) * 16 + ksi) * 512 + lane * 8);
#pragma unroll
        for (int f = 0; f < 2; ++f)
#pragma unroll
            for (int nf = 0; nf < 4; ++nf)
                acc[f][nf] = __builtin_amdgcn_mfma_f32_16x16x32_bf16(a[f], b[nf], acc[f][nf], 0, 0, 0);
    }
#pragma unroll 2
    for (int k0 = 256; k0 < 512; k0 += 32) {
        int kh = (k0 - 256) + kg * 8;
        int ksi = k0 >> 5;
        bf16x8 a[2], b[4];
#pragma unroll
        for (int f = 0; f < 2; ++f) {
            const float* hp = h + (size_t)rowA[f] * 256 + kh;
            float4 f0 = *(const float4*)hp, f1 = *(const float4*)(hp + 4);
            u16 tmp[8] = {f2bf(f0.x), f2bf(f0.y), f2bf(f0.z), f2bf(f0.w),
                          f2bf(f1.x), f2bf(f1.y), f2bf(f1.z), f2bf(f1.w)};
            a[f] = *(const bf16x8*)tmp;
        }
#pragma unroll
        for (int nf = 0; nf < 4; ++nf)
            b[nf] = *(const bf16x8*)(Kr + (size_t)((pt0 + nf) * 16 + ksi) * 512 + lane * 8);
#pragma unroll
        for (int f = 0; f < 2; ++f)
#pragma unroll
            for (int nf = 0; nf < 4; ++nf)
                acc[f][nf] = __builtin_amdgcn_mfma_f32_16x16x32_bf16(a[f], b[nf], acc[f][nf], 0, 0, 0);
    }

    __syncthreads();   // all waves done reading agg before in-place overwrite

    float b0[4], b1[4];
#pragma unroll
    for (int nf = 0; nf < 4; ++nf) {
        int p = pbase + nf * 16 + l15;
        b0[nf] = c0[p];
        b1[nf] = c1[p];
    }
#pragma unroll
    for (int f = 0; f < 2; ++f) {
#pragma unroll
        for (int r = 0; r < 4; ++r) {
            int row = m0 + f * 16 + kg * 4 + r;
            if (row >= N) continue;
            float wsv = wsum_arr[row];
#pragma unroll
            for (int nf = 0; nf < 4; ++nf) {
                int p = pbase + nf * 16 + l15;
                dio[(size_t)row * 256 + p] = acc[f][nf][r] + b0[nf] + b1[nf] * wsv;
            }
        }
    }
}

static inline size_t align4(size_t x) { return (x + 3) & ~(size_t)3; }
static inline int imax(int a, int b) { return a > b ? a : b; }

extern "C" void kernel_launch(void* const* d_in, const int* in_sizes, int n_in,
                              void* d_out, int out_size, void* d_ws, size_t ws_size,
                              hipStream_t stream) {
    const float* h       = (const float*)d_in[0];
    const int*   ei      = (const int*)d_in[1];   // (2,E) row-major
    const int*   et      = (const int*)d_in[2];
    const float* rel_emb = (const float*)d_in[3];
    const float* msg_w   = (const float*)d_in[4];
    const float* msg_b   = (const float*)d_in[5];
    const float* upd_w   = (const float*)d_in[6];
    const float* upd_b   = (const float*)d_in[7];
    const float* gate_w  = (const float*)d_in[8];
    const float* gate_b  = (const float*)d_in[9];

    const int N = in_sizes[0] / 256;
    const int E = in_sizes[2];
    const int R = in_sizes[3] / 256;

    // workspace layout (u32 units); total+deg_src+deg_dst contiguous for memset
    u32* ws = (u32*)d_ws;
    size_t o = 0;
    u32* total    = ws + o; o += 4;
    u32* deg_src  = ws + o; o += align4((size_t)N);
    u32* deg_dst  = ws + o; o += align4((size_t)N);
    u32* offs     = ws + o; o += align4((size_t)N);
    u32* cursor   = ws + o; o += align4((size_t)N);
    float* wsum   = (float*)(ws + o); o += align4((size_t)N);
    float* gate   = (float*)(ws + o); o += align4((size_t)R);
    uint2* edata  = (uint2*)(ws + o); o += (size_t)2 * E;
    u16* Kcomb    = (u16*)(ws + o); o += 524288;    // 8 x 256KB fragment-packed
    float* c0     = (float*)(ws + o); o += 256;
    float* c1     = (float*)(ws + o); o += 256;
    size_t need_base = o;
    u16* h_bf     = (u16*)(ws + o); o += (size_t)N * 128;
    u16* rel_bf   = (u16*)(ws + o); o += (size_t)R * 128;
    size_t need_bf = o;

    if (ws_size < need_base * 4) return;  // insufficient scratch -> fail loudly
    const bool use_bf = (ws_size >= need_bf * 4);

    float* out = (float*)d_out;
    u16* agg_bf = (u16*)d_out;   // bf16 rows at u16 stride 512 (half of each slot)

    // zero total + degree counters (contiguous)
    hipMemsetAsync(total, 0, (4 + 2 * align4((size_t)N)) * 4, stream);

    const int nbDeg  = (E + 255) / 256;
    const int nbGate = (R + 3) / 4;
    const int gridA  = 2 * imax(nbDeg, 256 + nbGate);
    prepA_kernel<<<gridA, 256, 0, stream>>>(
        msg_w, upd_w, upd_b, msg_b, rel_emb, gate_w, gate_b, ei, E,
        deg_src, deg_dst, gate, Kcomb, c0, c1, R, nbDeg, nbGate);

    alloc_kernel<<<(N + 255) / 256, 256, 0, stream>>>(deg_dst, offs, cursor, total, N);

    const int nbFill = (E + 255) / 256;
    const int nbRel  = use_bf ? (R * 32 + 255) / 256 : 0;
    const int nbH    = use_bf ? imax(256, nbFill - nbRel) : 0;
    const int gridB  = 2 * imax(nbFill, nbH + nbRel);
    if (use_bf) {
        prepB_kernel<1><<<gridB, 256, 0, stream>>>(
            ei, et, deg_src, deg_dst, gate, cursor, edata, h, rel_emb,
            h_bf, rel_bf, E, N, R, nbFill, nbH, nbRel);
    } else {
        prepB_kernel<0><<<gridB, 256, 0, stream>>>(
            ei, et, deg_src, deg_dst, gate, cursor, edata, h, rel_emb,
            h_bf, rel_bf, E, N, R, nbFill, nbH, nbRel);
    }

    if (use_bf) {
        agg_kernel<1><<<(N + 7) / 8, 256, 0, stream>>>(h, h_bf, rel_emb, rel_bf, offs,
                                                       deg_dst, edata, agg_bf, wsum, N);
        gemm_lds_kernel<<<(N + 31) / 32, 256, 0, stream>>>(out, agg_bf, Kcomb, h_bf,
                                                           wsum, c0, c1, N);
    } else {
        agg_kernel<0><<<(N + 7) / 8, 256, 0, stream>>>(h, h_bf, rel_emb, rel_bf, offs,
                                                       deg_dst, edata, agg_bf, wsum, N);
        gemm_reg_kernel<<<(N + 31) / 32, 256, 0, stream>>>(out, agg_bf, Kcomb, h,
                                                           wsum, c0, c1, N);
    }
}

// Round 17
// 228.116 us; speedup vs baseline: 1.0155x; 1.0155x over previous
//
#include <hip/hip_runtime.h>
#include <math.h>

typedef unsigned int u32;
typedef unsigned short u16;
typedef __attribute__((ext_vector_type(8))) short bf16x8;   // 8 bf16 in 4 VGPRs
typedef __attribute__((ext_vector_type(4))) float f32x4;

#define GLOBAL_AS __attribute__((address_space(1)))
#define LDS_AS __attribute__((address_space(3)))

__device__ __forceinline__ void gload_lds16(const void* g, void* s) {
    __builtin_amdgcn_global_load_lds((const GLOBAL_AS void*)g, (LDS_AS void*)s, 16, 0, 0);
}

__device__ inline u16 f2bf(float x) {  // round-to-nearest-even
    union { float f; u32 u; } v; v.f = x;
    u32 r = v.u + 0x7FFFu + ((v.u >> 16) & 1u);
    return (u16)(r >> 16);
}
__device__ inline float bf2f(u16 x) { return __uint_as_float((u32)x << 16); }
__device__ inline float bf_lo(u32 u) { return __uint_as_float(u << 16); }
__device__ inline float bf_hi(u32 u) { return __uint_as_float(u & 0xffff0000u); }

// Clifford sign/slot closed forms:  s = ob ^ ib ;
//   g = -1 iff (ob != 3 && ib == (3 ^ (ob & 1)))
__device__ __forceinline__ int cs_s(int ob, int ib) { return ob ^ ib; }
__device__ __forceinline__ float cs_g(int ob, int ib) {
    return ((ob != 3) && (ib == (3 ^ (ob & 1)))) ? -1.f : 1.f;
}

// ---------------------------------------------------------------------------
// Clifford GNN message passing, fully linearized:
//   agg[n] = sum_e w_e*(h[src] .* r[rel]),  w_e = gate(rel)*norm(e)
//   out    = (Ku.Km).agg + Ku.h + ws*(Ku.msg_b) + upd_b
// Round-15: fused prep kernels now INTERLEAVE roles across blockIdx (even =
// latency/atomic blocks, odd = streaming blocks) so every scheduler round
// holds both: the BW stream saturates HBM while atomic chains hide inside.
// (Round-14 put all fill blocks first -> zero overlap, prepB = sum of parts.)
// Pipeline: memset -> prepA{degree || kbuild|gate} -> alloc ->
//           prepB{fill || tobf_h|tobf_rel} -> agg -> gemm
// ---------------------------------------------------------------------------

// prepA: even blocks -> degree atomics (idx<nbDeg); odd -> kbuild row (idx<256)
// then gate (next nbGate). Grid = 2*max(nbDeg, 256+nbGate).
__global__ __launch_bounds__(256) void prepA_kernel(
    const float* __restrict__ msg_w, const float* __restrict__ upd_w,
    const float* __restrict__ upd_b, const float* __restrict__ msg_b,
    const float* __restrict__ rel_emb, const float* __restrict__ gate_w,
    const float* __restrict__ gate_b, const int* __restrict__ ei, int E,
    u32* __restrict__ deg_src, u32* __restrict__ deg_dst,
    float* __restrict__ gate, u16* __restrict__ Kcomb,
    float* __restrict__ c0, float* __restrict__ c1,
    int R, int nbDeg, int nbGate) {
    __shared__ __align__(16) u16 ms[16384];   // msg_w as bf16, 32KB
    __shared__ float U_s[256];
    __shared__ float wred[4];
    int tid = threadIdx.x;
    int idx = blockIdx.x >> 1;

    if (blockIdx.x & 1) {
        if (idx < 256) {
            // ---- kbuild: Kcomb row p (fragment-packed, 8 replicas) ----
            int p = idx;
            int j = (p & 3) * 64 + (p >> 2);
#pragma unroll
            for (int i = 0; i < 8; ++i) {
                int c8 = i * 256 + tid;
                const float* p8 = msg_w + (size_t)c8 * 8;
                float4 a = *(const float4*)(p8);
                float4 bb = *(const float4*)(p8 + 4);
                u16 tmp[8] = {f2bf(a.x), f2bf(a.y), f2bf(a.z), f2bf(a.w),
                              f2bf(bb.x), f2bf(bb.y), f2bf(bb.z), f2bf(bb.w)};
                *(uint4*)&ms[c8 * 8] = *(const uint4*)tmp;
            }
            int ib = tid >> 6, ic = tid & 63;
            {
                int obu = j >> 6;
                U_s[tid] = cs_g(obu, ib) * upd_w[cs_s(obu, ib) * 4096 + (j & 63) * 64 + ic];
            }
            __syncthreads();
            float acc = 0.f;
#pragma unroll
            for (int ob = 0; ob < 4; ++ob) {
                int s = cs_s(ob, ib);
                float gg = cs_g(ob, ib);
                const u16* mp = ms + s * 4096 + ic;
                const float* us = U_s + ob * 64;
                float a0 = 0.f;
#pragma unroll 8
                for (int oc = 0; oc < 64; ++oc) a0 += us[oc] * bf2f(mp[oc * 64]);
                acc += gg * a0;
            }
            u16 vA = f2bf(acc);          // element (p, k=tid)
            u16 vU = f2bf(U_s[tid]);     // element (p, k=tid+256)
            int pt = p >> 4, pl = p & 15;
            int kgA = (tid >> 3) & 3, elA = tid & 7;
            size_t addrA = (size_t)(pt * 16 + (tid >> 5)) * 512 + (kgA * 16 + pl) * 8 + elA;
            int ku = tid + 256;
            size_t addrU = (size_t)(pt * 16 + (ku >> 5)) * 512 + (kgA * 16 + pl) * 8 + elA;
#pragma unroll
            for (int r = 0; r < 8; ++r) {        // 8 replicas (one per XCD's L2)
                Kcomb[(size_t)r * 131072 + addrA] = vA;
                Kcomb[(size_t)r * 131072 + addrU] = vU;
            }
            float part = U_s[tid] * msg_b[tid];
            int lane = tid & 63, wv = tid >> 6;
#pragma unroll
            for (int d = 32; d > 0; d >>= 1) part += __shfl_down(part, d);
            if (lane == 0) wred[wv] = part;
            __syncthreads();
            if (tid == 0) { c1[p] = wred[0] + wred[1] + wred[2] + wred[3]; c0[p] = upd_b[j]; }
            return;
        }
        int gb = idx - 256;
        if (gb < nbGate) {
            int wv = tid >> 6, lane = tid & 63;
            int r = gb * 4 + wv;
            if (r >= R) return;
            float4 rv = *(const float4*)(rel_emb + (size_t)r * 256 + lane * 4);
            float s = 0.f;
            float rvv[4] = {rv.x, rv.y, rv.z, rv.w};
#pragma unroll
            for (int c = 0; c < 4; ++c) {
                int jj = lane * 4 + c;
                s += rvv[c] * gate_w[(jj & 63) * 4 + (jj >> 6)];
            }
#pragma unroll
            for (int d = 32; d > 0; d >>= 1) s += __shfl_down(s, d);
            if (lane == 0) gate[r] = 1.0f / (1.0f + expf(-(s + gate_b[0])));
        }
        return;
    }
    // even: degree atomics
    if (idx < nbDeg) {
        int e = idx * 256 + tid;
        if (e < E) {
            atomicAdd(&deg_src[ei[e]], 1u);
            atomicAdd(&deg_dst[ei[E + e]], 1u);
        }
    }
}

// Parallel bucket allocator (order irrelevant, only disjointness matters).
__global__ void alloc_kernel(const u32* __restrict__ deg, u32* __restrict__ offs,
                             u32* __restrict__ cursor, u32* __restrict__ total, int N) {
    __shared__ u32 wt[4];
    __shared__ u32 bbase;
    int tid = threadIdx.x, lane = tid & 63, wv = tid >> 6;
    int i = blockIdx.x * 256 + tid;
    u32 d = (i < N) ? deg[i] : 0u;
    u32 sc = d;
#pragma unroll
    for (int s = 1; s < 64; s <<= 1) { u32 o = __shfl_up(sc, s); if (lane >= s) sc += o; }
    if (lane == 63) wt[wv] = sc;
    __syncthreads();
    if (tid == 0) bbase = atomicAdd(total, wt[0] + wt[1] + wt[2] + wt[3]);
    __syncthreads();
    u32 wpre = 0;
    for (int w = 0; w < wv; ++w) wpre += wt[w];
    u32 off = bbase + wpre + sc - d;
    if (i < N) { offs[i] = off; cursor[i] = off; }
}

// prepB: even blocks -> fill (idx<nbFill); odd -> h-stream (idx<nbH,
// grid-stride) then rel-stream. Grid = 2*max(nbFill, nbH+nbRel).
template <int BF>
__global__ __launch_bounds__(256) void prepB_kernel(
    const int* __restrict__ ei, const int* __restrict__ et,
    const u32* __restrict__ deg_src, const u32* __restrict__ deg_dst,
    const float* __restrict__ gate, u32* __restrict__ cursor,
    uint2* __restrict__ edata,
    const float* __restrict__ h, const float* __restrict__ rel_emb,
    u16* __restrict__ h_bf, u16* __restrict__ rel_bf,
    int E, int N, int R, int nbFill, int nbH, int nbRel) {
    int tid = threadIdx.x;
    int idx = blockIdx.x >> 1;
    if (blockIdx.x & 1) {
        if (BF && idx < nbH) {
            int n8 = N * 32;
            for (int i = idx * 256 + tid; i < n8; i += nbH * 256) {
                const float* p8 = h + (size_t)i * 8;
                float4 a = *(const float4*)(p8);
                float4 bb = *(const float4*)(p8 + 4);
                u16 tmp[8] = {f2bf(a.x), f2bf(a.y), f2bf(a.z), f2bf(a.w),
                              f2bf(bb.x), f2bf(bb.y), f2bf(bb.z), f2bf(bb.w)};
                *(uint4*)(h_bf + (size_t)i * 8) = *(const uint4*)tmp;
            }
            return;
        }
        int rb = idx - (BF ? nbH : 0);
        if (BF && rb < nbRel) {
            int i = rb * 256 + tid;
            if (i < R * 32) {
                const float* p8 = rel_emb + (size_t)i * 8;
                float4 a = *(const float4*)(p8);
                float4 bb = *(const float4*)(p8 + 4);
                u16 tmp[8] = {f2bf(a.x), f2bf(a.y), f2bf(a.z), f2bf(a.w),
                              f2bf(bb.x), f2bf(bb.y), f2bf(bb.z), f2bf(bb.w)};
                *(uint4*)(rel_bf + (size_t)i * 8) = *(const uint4*)tmp;
            }
        }
        return;
    }
    // even: bucket-fill
    if (idx < nbFill) {
        int e = idx * 256 + tid;
        if (e < E) {
            int src = ei[e];
            int dst = ei[E + e];
            int rel = et[e];
            float w = gate[rel] *
                      rsqrtf(fmaxf((float)deg_src[src] * (float)deg_dst[dst], 1.0f));
            u32 pos = atomicAdd(&cursor[dst], 1u);
            edata[pos] = make_uint2((u32)src | ((u32)rel << 18), __float_as_uint(w));
        }
    }
}

// 2 nodes per wave (lanes 0-31 = node A, 32-63 = node B; 16B/lane).
// Predicated x4-unrolled edge loop: tail edges use clamped index (cache-hit
// duplicate) with zero weight. Every lane accumulates the full per-node wsum;
// lane l32==0 writes it directly (no cross-lane reduction).
template <int BF>
__global__ __launch_bounds__(256) void agg_kernel(
    const float* __restrict__ h, const u16* __restrict__ h_bf,
    const float* __restrict__ rel_emb, const u16* __restrict__ rel_bf,
    const u32* __restrict__ offs, const u32* __restrict__ deg_dst,
    const uint2* __restrict__ edata,
    u16* __restrict__ agg_bf, float* __restrict__ wsum_arr, int N) {
    int wv = threadIdx.x >> 6, lane = threadIdx.x & 63;
    int half = lane >> 5, l32 = lane & 31;
    int n = (blockIdx.x * 4 + wv) * 2 + half;
    bool valid = n < N;
    u32 off = valid ? offs[n] : 0u;
    u32 dd  = valid ? deg_dst[n] : 0u;
    float acc[8];
#pragma unroll
    for (int j = 0; j < 8; ++j) acc[j] = 0.f;
    float wsum = 0.f;

    for (u32 e = 0; e < dd; e += 4) {
        uint2 d[4];
        uint4 hv[4], rv[4];
        float wq[4];
#pragma unroll
        for (int q = 0; q < 4; ++q) {
            u32 idx = e + q;
            u32 cl = (idx < dd) ? idx : (dd - 1);   // clamp -> dup line, cache hit
            d[q] = edata[off + cl];
            wq[q] = (idx < dd) ? __uint_as_float(d[q].y) : 0.f;
        }
#pragma unroll
        for (int q = 0; q < 4; ++q) {
            u32 src = d[q].x & 0x3FFFFu, rel = d[q].x >> 18;
            if (BF) {
                hv[q] = *(const uint4*)(h_bf + (size_t)src * 256 + l32 * 8);
                rv[q] = *(const uint4*)(rel_bf + (size_t)rel * 256 + l32 * 8);
            } else {
                const float* hp = h + (size_t)src * 256 + l32 * 8;
                const float* rp = rel_emb + (size_t)rel * 256 + l32 * 8;
                float4 hf0 = *(const float4*)hp, hf1 = *(const float4*)(hp + 4);
                float4 rf0 = *(const float4*)rp, rf1 = *(const float4*)(rp + 4);
                u16 th[8] = {f2bf(hf0.x), f2bf(hf0.y), f2bf(hf0.z), f2bf(hf0.w),
                             f2bf(hf1.x), f2bf(hf1.y), f2bf(hf1.z), f2bf(hf1.w)};
                u16 tr[8] = {f2bf(rf0.x), f2bf(rf0.y), f2bf(rf0.z), f2bf(rf0.w),
                             f2bf(rf1.x), f2bf(rf1.y), f2bf(rf1.z), f2bf(rf1.w)};
                hv[q] = *(const uint4*)th;
                rv[q] = *(const uint4*)tr;
            }
        }
#pragma unroll
        for (int q = 0; q < 4; ++q) {
            float w = wq[q];
            u32 hu[4] = {hv[q].x, hv[q].y, hv[q].z, hv[q].w};
            u32 ru[4] = {rv[q].x, rv[q].y, rv[q].z, rv[q].w};
#pragma unroll
            for (int c = 0; c < 4; ++c) {
                acc[c * 2 + 0] += w * bf_lo(hu[c]) * bf_lo(ru[c]);
                acc[c * 2 + 1] += w * bf_hi(hu[c]) * bf_hi(ru[c]);
            }
            wsum += w;
        }
    }

    if (valid) {
        u32 outw[4];
#pragma unroll
        for (int c = 0; c < 4; ++c)
            outw[c] = (u32)f2bf(acc[c * 2]) | ((u32)f2bf(acc[c * 2 + 1]) << 16);
        *(uint4*)(agg_bf + (size_t)n * 512 + l32 * 8) = *(const uint4*)outw;
        if (l32 == 0) wsum_arr[n] = wsum;   // already the full sum per lane
    }
}

// LDS-staged K=512 GEMM. Block = 32 rows x 256 cols; 4 waves, each 32x64.
// x=[agg|h] staged async into swizzled LDS via global_load_lds (dest linear,
// per-lane SOURCE pre-swizzled). B = fragment-packed Kcomb (1KB coalesced
// bursts) from the XCD-local replica.
// out[row][p] = acc + c0[p] + c1[p]*wsum[row].
__global__ __launch_bounds__(256, 4) void gemm_lds_kernel(
    float* __restrict__ dio, const u16* __restrict__ agg_bf,
    const u16* __restrict__ Kcomb, const u16* __restrict__ h_bf,
    const float* __restrict__ wsum_arr,
    const float* __restrict__ c0, const float* __restrict__ c1, int N) {
    __shared__ __align__(16) u16 xs[32 * 512];   // 32 KiB
    const int lane = threadIdx.x & 63;
    const int wv = threadIdx.x >> 6;      // wave owns output cols [wv*64, +64)
    const int l15 = lane & 15;
    const int kg = lane >> 4;             // k-group 0..3
    const int m0 = blockIdx.x * 32;
    const int pbase = wv * 64;
    const int pt0 = wv * 4;               // first B fragment-tile index
    const u16* Kr = Kcomb + (size_t)(blockIdx.x & 7) * 131072;  // XCD replica

    // ---- async stage x=[agg|h] rows -> swizzled LDS (1 row / issue) ----
    {
        int j0 = lane * 8;                       // dest u16 offset in row
#pragma unroll
        for (int i = 0; i < 8; ++i) {
            int m = i * 4 + wv;                  // 0..31
            int row = m0 + m;
            if (row >= N) row = N - 1;           // clamp; masked at store
            int ks = j0 ^ ((m & 7) << 3);        // pre-swizzled source k
            const u16* src = (j0 < 256)
                ? agg_bf + (size_t)row * 512 + ks
                : h_bf + (size_t)row * 256 + (ks - 256);
            gload_lds16(src, &xs[m * 512]);
        }
    }
    __syncthreads();   // drains global_load_lds; also fences in-place d_out use

    f32x4 acc[2][4];
#pragma unroll
    for (int f = 0; f < 2; ++f)
#pragma unroll
        for (int nf = 0; nf < 4; ++nf) acc[f][nf] = (f32x4)(0.f);

    const int swz = (l15 & 7) << 3;
#pragma unroll 4
    for (int k0 = 0; k0 < 512; k0 += 32) {
        int kk = k0 + kg * 8;
        int ksi = k0 >> 5;
        bf16x8 a[2], b[4];
#pragma unroll
        for (int f = 0; f < 2; ++f)
            a[f] = *(const bf16x8*)&xs[(f * 16 + l15) * 512 + (kk ^ swz)];
#pragma unroll
        for (int nf = 0; nf < 4; ++nf)
            b[nf] = *(const bf16x8*)(Kr + (size_t)((pt0 + nf) * 16 + ksi) * 512 + lane * 8);
#pragma unroll
        for (int f = 0; f < 2; ++f)
#pragma unroll
            for (int nf = 0; nf < 4; ++nf)
                acc[f][nf] = __builtin_amdgcn_mfma_f32_16x16x32_bf16(a[f], b[nf], acc[f][nf], 0, 0, 0);
    }

    // ---- epilogue: y = acc + c0[p] + c1[p]*wsum[row] ----
    float b0[4], b1[4];
#pragma unroll
    for (int nf = 0; nf < 4; ++nf) {
        int p = pbase + nf * 16 + l15;
        b0[nf] = c0[p];
        b1[nf] = c1[p];
    }
#pragma unroll
    for (int f = 0; f < 2; ++f) {
#pragma unroll
        for (int r = 0; r < 4; ++r) {
            int row = m0 + f * 16 + kg * 4 + r;
            if (row >= N) continue;
            float wsv = wsum_arr[row];
#pragma unroll
            for (int nf = 0; nf < 4; ++nf) {
                int p = pbase + nf * 16 + l15;
                dio[(size_t)row * 256 + p] = acc[f][nf][r] + b0[nf] + b1[nf] * wsv;
            }
        }
    }
}

// Fallback (no bf16 workspace): register GEMM, packed-B, barrier before epilogue.
__global__ __launch_bounds__(256, 4) void gemm_reg_kernel(
    float* __restrict__ dio, const u16* __restrict__ agg_bf,
    const u16* __restrict__ Kcomb,
    const float* __restrict__ h,
    const float* __restrict__ wsum_arr,
    const float* __restrict__ c0, const float* __restrict__ c1, int N) {
    const int lane = threadIdx.x & 63;
    const int wv = threadIdx.x >> 6;
    const int l15 = lane & 15;
    const int kg = lane >> 4;
    const int m0 = blockIdx.x * 32;
    const int pbase = wv * 64;
    const int pt0 = wv * 4;

    f32x4 acc[2][4];
#pragma unroll
    for (int f = 0; f < 2; ++f)
#pragma unroll
        for (int nf = 0; nf < 4; ++nf) acc[f][nf] = (f32x4)(0.f);

    int rowA[2];
#pragma unroll
    for (int f = 0; f < 2; ++f) {
        int r = m0 + f * 16 + l15;
        rowA[f] = (r < N) ? r : (N - 1);
    }
    const u16* Kr = Kcomb + (size_t)(blockIdx.x & 7) * 131072;

#pragma unroll 2
    for (int k0 = 0; k0 < 256; k0 += 32) {
        int kk = k0 + kg * 8;
        int ksi = k0 >> 5;
        bf16x8 a[2], b[4];
#pragma unroll
        for (int f = 0; f < 2; ++f)
            a[f] = *(const bf16x8*)(agg_bf + (size_t)rowA[f] * 512 + kk);
#pragma unroll
        for (int nf = 0; nf < 4; ++nf)
            b[nf] = *(const bf16x8*)(Kr + (size_t)((pt0 + nf) * 16 + ksi) * 512 + lane * 8);
#pragma unroll
        for (int f = 0; f < 2; ++f)
#pragma unroll
            for (int nf = 0; nf < 4; ++nf)
                acc[f][nf] = __builtin_amdgcn_mfma_f32_16x16x32_bf16(a[f], b[nf], acc[f][nf], 0, 0, 0);
    }
#pragma unroll 2
    for (int k0 = 256; k0 < 512; k0 += 32) {
        int kh = (k0 - 256) + kg * 8;
        int ksi = k0 >> 5;
        bf16x8 a[2], b[4];
#pragma unroll
        for (int f = 0; f < 2; ++f) {
            const float* hp = h + (size_t)rowA[f] * 256 + kh;
            float4 f0 = *(const float4*)hp, f1 = *(const float4*)(hp + 4);
            u16 tmp[8] = {f2bf(f0.x), f2bf(f0.y), f2bf(f0.z), f2bf(f0.w),
                          f2bf(f1.x), f2bf(f1.y), f2bf(f1.z), f2bf(f1.w)};
            a[f] = *(const bf16x8*)tmp;
        }
#pragma unroll
        for (int nf = 0; nf < 4; ++nf)
            b[nf] = *(const bf16x8*)(Kr + (size_t)((pt0 + nf) * 16 + ksi) * 512 + lane * 8);
#pragma unroll
        for (int f = 0; f < 2; ++f)
#pragma unroll
            for (int nf = 0; nf < 4; ++nf)
                acc[f][nf] = __builtin_amdgcn_mfma_f32_16x16x32_bf16(a[f], b[nf], acc[f][nf], 0, 0, 0);
    }

    __syncthreads();   // all waves done reading agg before in-place overwrite

    float b0[4], b1[4];
#pragma unroll
    for (int nf = 0; nf < 4; ++nf) {
        int p = pbase + nf * 16 + l15;
        b0[nf] = c0[p];
        b1[nf] = c1[p];
    }
#pragma unroll
    for (int f = 0; f < 2; ++f) {
#pragma unroll
        for (int r = 0; r < 4; ++r) {
            int row = m0 + f * 16 + kg * 4 + r;
            if (row >= N) continue;
            float wsv = wsum_arr[row];
#pragma unroll
            for (int nf = 0; nf < 4; ++nf) {
                int p = pbase + nf * 16 + l15;
                dio[(size_t)row * 256 + p] = acc[f][nf][r] + b0[nf] + b1[nf] * wsv;
            }
        }
    }
}

static inline size_t align4(size_t x) { return (x + 3) & ~(size_t)3; }
static inline int imax(int a, int b) { return a > b ? a : b; }

extern "C" void kernel_launch(void* const* d_in, const int* in_sizes, int n_in,
                              void* d_out, int out_size, void* d_ws, size_t ws_size,
                              hipStream_t stream) {
    const float* h       = (const float*)d_in[0];
    const int*   ei      = (const int*)d_in[1];   // (2,E) row-major
    const int*   et      = (const int*)d_in[2];
    const float* rel_emb = (const float*)d_in[3];
    const float* msg_w   = (const float*)d_in[4];
    const float* msg_b   = (const float*)d_in[5];
    const float* upd_w   = (const float*)d_in[6];
    const float* upd_b   = (const float*)d_in[7];
    const float* gate_w  = (const float*)d_in[8];
    const float* gate_b  = (const float*)d_in[9];

    const int N = in_sizes[0] / 256;
    const int E = in_sizes[2];
    const int R = in_sizes[3] / 256;

    // workspace layout (u32 units); total+deg_src+deg_dst contiguous for memset
    u32* ws = (u32*)d_ws;
    size_t o = 0;
    u32* total    = ws + o; o += 4;
    u32* deg_src  = ws + o; o += align4((size_t)N);
    u32* deg_dst  = ws + o; o += align4((size_t)N);
    u32* offs     = ws + o; o += align4((size_t)N);
    u32* cursor   = ws + o; o += align4((size_t)N);
    float* wsum   = (float*)(ws + o); o += align4((size_t)N);
    float* gate   = (float*)(ws + o); o += align4((size_t)R);
    uint2* edata  = (uint2*)(ws + o); o += (size_t)2 * E;
    u16* Kcomb    = (u16*)(ws + o); o += 524288;    // 8 x 256KB fragment-packed
    float* c0     = (float*)(ws + o); o += 256;
    float* c1     = (float*)(ws + o); o += 256;
    size_t need_base = o;
    u16* h_bf     = (u16*)(ws + o); o += (size_t)N * 128;
    u16* rel_bf   = (u16*)(ws + o); o += (size_t)R * 128;
    size_t need_bf = o;

    if (ws_size < need_base * 4) return;  // insufficient scratch -> fail loudly
    const bool use_bf = (ws_size >= need_bf * 4);

    float* out = (float*)d_out;
    u16* agg_bf = (u16*)d_out;   // bf16 rows at u16 stride 512 (half of each slot)

    // zero total + degree counters (contiguous)
    hipMemsetAsync(total, 0, (4 + 2 * align4((size_t)N)) * 4, stream);

    const int nbDeg  = (E + 255) / 256;
    const int nbGate = (R + 3) / 4;
    const int gridA  = 2 * imax(nbDeg, 256 + nbGate);
    prepA_kernel<<<gridA, 256, 0, stream>>>(
        msg_w, upd_w, upd_b, msg_b, rel_emb, gate_w, gate_b, ei, E,
        deg_src, deg_dst, gate, Kcomb, c0, c1, R, nbDeg, nbGate);

    alloc_kernel<<<(N + 255) / 256, 256, 0, stream>>>(deg_dst, offs, cursor, total, N);

    const int nbFill = (E + 255) / 256;
    const int nbRel  = use_bf ? (R * 32 + 255) / 256 : 0;
    const int nbH    = use_bf ? imax(256, nbFill - nbRel) : 0;
    const int gridB  = 2 * imax(nbFill, nbH + nbRel);
    if (use_bf) {
        prepB_kernel<1><<<gridB, 256, 0, stream>>>(
            ei, et, deg_src, deg_dst, gate, cursor, edata, h, rel_emb,
            h_bf, rel_bf, E, N, R, nbFill, nbH, nbRel);
    } else {
        prepB_kernel<0><<<gridB, 256, 0, stream>>>(
            ei, et, deg_src, deg_dst, gate, cursor, edata, h, rel_emb,
            h_bf, rel_bf, E, N, R, nbFill, nbH, nbRel);
    }

    if (use_bf) {
        agg_kernel<1><<<(N + 7) / 8, 256, 0, stream>>>(h, h_bf, rel_emb, rel_bf, offs,
                                                       deg_dst, edata, agg_bf, wsum, N);
        gemm_lds_kernel<<<(N + 31) / 32, 256, 0, stream>>>(out, agg_bf, Kcomb, h_bf,
                                                           wsum, c0, c1, N);
    } else {
        agg_kernel<0><<<(N + 7) / 8, 256, 0, stream>>>(h, h_bf, rel_emb, rel_bf, offs,
                                                       deg_dst, edata, agg_bf, wsum, N);
        gemm_reg_kernel<<<(N + 31) / 32, 256, 0, stream>>>(out, agg_bf, Kcomb, h,
                                                           wsum, c0, c1, N);
    }
}

// Round 18
// 222.864 us; speedup vs baseline: 1.0395x; 1.0236x over previous
//
#include <hip/hip_runtime.h>
#include <math.h>

typedef unsigned int u32;
typedef unsigned short u16;
typedef __attribute__((ext_vector_type(8))) short bf16x8;   // 8 bf16 in 4 VGPRs
typedef __attribute__((ext_vector_type(4))) float f32x4;

__device__ inline u16 f2bf(float x) {  // round-to-nearest-even
    union { float f; u32 u; } v; v.f = x;
    u32 r = v.u + 0x7FFFu + ((v.u >> 16) & 1u);
    return (u16)(r >> 16);
}
__device__ inline float bf2f(u16 x) { return __uint_as_float((u32)x << 16); }
__device__ inline float bf_lo(u32 u) { return __uint_as_float(u << 16); }
__device__ inline float bf_hi(u32 u) { return __uint_as_float(u & 0xffff0000u); }

// Clifford sign/slot closed forms:  s = ob ^ ib ;
//   g = -1 iff (ob != 3 && ib == (3 ^ (ob & 1)))
__device__ __forceinline__ int cs_s(int ob, int ib) { return ob ^ ib; }
__device__ __forceinline__ float cs_g(int ob, int ib) {
    return ((ob != 3) && (ib == (3 ^ (ob & 1)))) ? -1.f : 1.f;
}

// ---------------------------------------------------------------------------
// Clifford GNN message passing, fully linearized:
//   agg[n] = sum_e w_e*(h[src] .* r[rel]),  w_e = gate(rel)*norm(e)
//   out    = (Ku.Km).agg + Ku.h + ws*(Ku.msg_b) + upd_b
// Round-18: agg FUSED into the GEMM block (r3 retry under new conditions:
// half-wave gathers + single-pass K=512 GEMM + 4 blocks/CU). Per 32-node
// block: 4 rounds of half-wave gathers write bf16 straight into the swizzled
// LDS x-tile ([agg|h] rows), one barrier, MFMA K-loop, fp32 store. Removes
// the 51MB agg write + re-read, wsum array, and one dispatch.
// Pipeline: memset -> prepA{degree || kbuild|gate} -> alloc ->
//           prepB{fill || tobf_h|tobf_rel} -> aggemm
// ---------------------------------------------------------------------------

// prepA: even blocks -> degree atomics (idx<nbDeg); odd -> kbuild row (idx<256)
// then gate (next nbGate). Grid = 2*max(nbDeg, 256+nbGate).
__global__ __launch_bounds__(256) void prepA_kernel(
    const float* __restrict__ msg_w, const float* __restrict__ upd_w,
    const float* __restrict__ upd_b, const float* __restrict__ msg_b,
    const float* __restrict__ rel_emb, const float* __restrict__ gate_w,
    const float* __restrict__ gate_b, const int* __restrict__ ei, int E,
    u32* __restrict__ deg_src, u32* __restrict__ deg_dst,
    float* __restrict__ gate, u16* __restrict__ Kcomb,
    float* __restrict__ c0, float* __restrict__ c1,
    int R, int nbDeg, int nbGate) {
    __shared__ __align__(16) u16 ms[16384];   // msg_w as bf16, 32KB
    __shared__ float U_s[256];
    __shared__ float wred[4];
    int tid = threadIdx.x;
    int idx = blockIdx.x >> 1;

    if (blockIdx.x & 1) {
        if (idx < 256) {
            // ---- kbuild: Kcomb row p (fragment-packed, 8 replicas) ----
            int p = idx;
            int j = (p & 3) * 64 + (p >> 2);
#pragma unroll
            for (int i = 0; i < 8; ++i) {
                int c8 = i * 256 + tid;
                const float* p8 = msg_w + (size_t)c8 * 8;
                float4 a = *(const float4*)(p8);
                float4 bb = *(const float4*)(p8 + 4);
                u16 tmp[8] = {f2bf(a.x), f2bf(a.y), f2bf(a.z), f2bf(a.w),
                              f2bf(bb.x), f2bf(bb.y), f2bf(bb.z), f2bf(bb.w)};
                *(uint4*)&ms[c8 * 8] = *(const uint4*)tmp;
            }
            int ib = tid >> 6, ic = tid & 63;
            {
                int obu = j >> 6;
                U_s[tid] = cs_g(obu, ib) * upd_w[cs_s(obu, ib) * 4096 + (j & 63) * 64 + ic];
            }
            __syncthreads();
            float acc = 0.f;
#pragma unroll
            for (int ob = 0; ob < 4; ++ob) {
                int s = cs_s(ob, ib);
                float gg = cs_g(ob, ib);
                const u16* mp = ms + s * 4096 + ic;
                const float* us = U_s + ob * 64;
                float a0 = 0.f;
#pragma unroll 8
                for (int oc = 0; oc < 64; ++oc) a0 += us[oc] * bf2f(mp[oc * 64]);
                acc += gg * a0;
            }
            u16 vA = f2bf(acc);          // element (p, k=tid)
            u16 vU = f2bf(U_s[tid]);     // element (p, k=tid+256)
            int pt = p >> 4, pl = p & 15;
            int kgA = (tid >> 3) & 3, elA = tid & 7;
            size_t addrA = (size_t)(pt * 16 + (tid >> 5)) * 512 + (kgA * 16 + pl) * 8 + elA;
            int ku = tid + 256;
            size_t addrU = (size_t)(pt * 16 + (ku >> 5)) * 512 + (kgA * 16 + pl) * 8 + elA;
#pragma unroll
            for (int r = 0; r < 8; ++r) {        // 8 replicas (one per XCD's L2)
                Kcomb[(size_t)r * 131072 + addrA] = vA;
                Kcomb[(size_t)r * 131072 + addrU] = vU;
            }
            float part = U_s[tid] * msg_b[tid];
            int lane = tid & 63, wv = tid >> 6;
#pragma unroll
            for (int d = 32; d > 0; d >>= 1) part += __shfl_down(part, d);
            if (lane == 0) wred[wv] = part;
            __syncthreads();
            if (tid == 0) { c1[p] = wred[0] + wred[1] + wred[2] + wred[3]; c0[p] = upd_b[j]; }
            return;
        }
        int gb = idx - 256;
        if (gb < nbGate) {
            int wv = tid >> 6, lane = tid & 63;
            int r = gb * 4 + wv;
            if (r >= R) return;
            float4 rv = *(const float4*)(rel_emb + (size_t)r * 256 + lane * 4);
            float s = 0.f;
            float rvv[4] = {rv.x, rv.y, rv.z, rv.w};
#pragma unroll
            for (int c = 0; c < 4; ++c) {
                int jj = lane * 4 + c;
                s += rvv[c] * gate_w[(jj & 63) * 4 + (jj >> 6)];
            }
#pragma unroll
            for (int d = 32; d > 0; d >>= 1) s += __shfl_down(s, d);
            if (lane == 0) gate[r] = 1.0f / (1.0f + expf(-(s + gate_b[0])));
        }
        return;
    }
    // even: degree atomics
    if (idx < nbDeg) {
        int e = idx * 256 + tid;
        if (e < E) {
            atomicAdd(&deg_src[ei[e]], 1u);
            atomicAdd(&deg_dst[ei[E + e]], 1u);
        }
    }
}

// Parallel bucket allocator (order irrelevant, only disjointness matters).
__global__ void alloc_kernel(const u32* __restrict__ deg, u32* __restrict__ offs,
                             u32* __restrict__ cursor, u32* __restrict__ total, int N) {
    __shared__ u32 wt[4];
    __shared__ u32 bbase;
    int tid = threadIdx.x, lane = tid & 63, wv = tid >> 6;
    int i = blockIdx.x * 256 + tid;
    u32 d = (i < N) ? deg[i] : 0u;
    u32 sc = d;
#pragma unroll
    for (int s = 1; s < 64; s <<= 1) { u32 o = __shfl_up(sc, s); if (lane >= s) sc += o; }
    if (lane == 63) wt[wv] = sc;
    __syncthreads();
    if (tid == 0) bbase = atomicAdd(total, wt[0] + wt[1] + wt[2] + wt[3]);
    __syncthreads();
    u32 wpre = 0;
    for (int w = 0; w < wv; ++w) wpre += wt[w];
    u32 off = bbase + wpre + sc - d;
    if (i < N) { offs[i] = off; cursor[i] = off; }
}

// prepB: even blocks -> fill (idx<nbFill); odd -> h-stream (idx<nbH,
// grid-stride) then rel-stream. Grid = 2*max(nbFill, nbH+nbRel).
template <int BF>
__global__ __launch_bounds__(256) void prepB_kernel(
    const int* __restrict__ ei, const int* __restrict__ et,
    const u32* __restrict__ deg_src, const u32* __restrict__ deg_dst,
    const float* __restrict__ gate, u32* __restrict__ cursor,
    uint2* __restrict__ edata,
    const float* __restrict__ h, const float* __restrict__ rel_emb,
    u16* __restrict__ h_bf, u16* __restrict__ rel_bf,
    int E, int N, int R, int nbFill, int nbH, int nbRel) {
    int tid = threadIdx.x;
    int idx = blockIdx.x >> 1;
    if (blockIdx.x & 1) {
        if (BF && idx < nbH) {
            int n8 = N * 32;
            for (int i = idx * 256 + tid; i < n8; i += nbH * 256) {
                const float* p8 = h + (size_t)i * 8;
                float4 a = *(const float4*)(p8);
                float4 bb = *(const float4*)(p8 + 4);
                u16 tmp[8] = {f2bf(a.x), f2bf(a.y), f2bf(a.z), f2bf(a.w),
                              f2bf(bb.x), f2bf(bb.y), f2bf(bb.z), f2bf(bb.w)};
                *(uint4*)(h_bf + (size_t)i * 8) = *(const uint4*)tmp;
            }
            return;
        }
        int rb = idx - (BF ? nbH : 0);
        if (BF && rb < nbRel) {
            int i = rb * 256 + tid;
            if (i < R * 32) {
                const float* p8 = rel_emb + (size_t)i * 8;
                float4 a = *(const float4*)(p8);
                float4 bb = *(const float4*)(p8 + 4);
                u16 tmp[8] = {f2bf(a.x), f2bf(a.y), f2bf(a.z), f2bf(a.w),
                              f2bf(bb.x), f2bf(bb.y), f2bf(bb.z), f2bf(bb.w)};
                *(uint4*)(rel_bf + (size_t)i * 8) = *(const uint4*)tmp;
            }
        }
        return;
    }
    // even: bucket-fill
    if (idx < nbFill) {
        int e = idx * 256 + tid;
        if (e < E) {
            int src = ei[e];
            int dst = ei[E + e];
            int rel = et[e];
            float w = gate[rel] *
                      rsqrtf(fmaxf((float)deg_src[src] * (float)deg_dst[dst], 1.0f));
            u32 pos = atomicAdd(&cursor[dst], 1u);
            edata[pos] = make_uint2((u32)src | ((u32)rel << 18), __float_as_uint(w));
        }
    }
}

// Fused aggregate + GEMM. Block = 32 nodes; 4 waves.
// Gather phase: 4 rounds; each half-wave (32 lanes, 16B/lane) aggregates one
// node (predicated x4-unrolled edge loop, clamp+zero-weight tail) and writes
// the bf16 agg row + the node's h_bf row straight into the swizzled LDS
// x-tile (xs[m*512 + (k ^ ((m&7)<<3))]). wsum -> LDS. One barrier.
// GEMM: K=512, B = fragment-packed Kcomb (1KB coalesced bursts, XCD-local
// replica). out[row][p] = acc + c0[p] + c1[p]*ws_l[m]  (fp32, written once).
template <int BF>
__global__ __launch_bounds__(256, 4) void aggemm_kernel(
    float* __restrict__ dio,
    const float* __restrict__ h, const u16* __restrict__ h_bf,
    const float* __restrict__ rel_emb, const u16* __restrict__ rel_bf,
    const u16* __restrict__ Kcomb,
    const u32* __restrict__ offs, const u32* __restrict__ deg_dst,
    const uint2* __restrict__ edata,
    const float* __restrict__ c0, const float* __restrict__ c1, int N) {
    __shared__ __align__(16) u16 xs[32 * 512];   // 32 KiB x-tile [agg|h]
    __shared__ float ws_l[32];
    const int lane = threadIdx.x & 63;
    const int wv = threadIdx.x >> 6;
    const int l15 = lane & 15;
    const int kg = lane >> 4;
    const int half = lane >> 5, l32 = lane & 31;
    const int m0 = blockIdx.x * 32;
    const int pbase = wv * 64;
    const int pt0 = wv * 4;
    const u16* Kr = Kcomb + (size_t)(blockIdx.x & 7) * 131072;  // XCD replica

    // ---- gather/aggregate phase: 4 rounds, 2 nodes per wave per round ----
    for (int rnd = 0; rnd < 4; ++rnd) {
        int m = wv * 8 + rnd * 2 + half;     // 0..31
        int n = m0 + m;
        bool valid = n < N;
        u32 off = valid ? offs[n] : 0u;
        u32 dd  = valid ? deg_dst[n] : 0u;
        float acc[8];
#pragma unroll
        for (int j = 0; j < 8; ++j) acc[j] = 0.f;
        float wsum = 0.f;

        for (u32 e = 0; e < dd; e += 4) {
            uint2 d[4];
            uint4 hv[4], rv[4];
            float wq[4];
#pragma unroll
            for (int q = 0; q < 4; ++q) {
                u32 idx = e + q;
                u32 cl = (idx < dd) ? idx : (dd - 1);   // clamp -> cache-hit dup
                d[q] = edata[off + cl];
                wq[q] = (idx < dd) ? __uint_as_float(d[q].y) : 0.f;
            }
#pragma unroll
            for (int q = 0; q < 4; ++q) {
                u32 src = d[q].x & 0x3FFFFu, rel = d[q].x >> 18;
                if (BF) {
                    hv[q] = *(const uint4*)(h_bf + (size_t)src * 256 + l32 * 8);
                    rv[q] = *(const uint4*)(rel_bf + (size_t)rel * 256 + l32 * 8);
                } else {
                    const float* hp = h + (size_t)src * 256 + l32 * 8;
                    const float* rp = rel_emb + (size_t)rel * 256 + l32 * 8;
                    float4 hf0 = *(const float4*)hp, hf1 = *(const float4*)(hp + 4);
                    float4 rf0 = *(const float4*)rp, rf1 = *(const float4*)(rp + 4);
                    u16 th[8] = {f2bf(hf0.x), f2bf(hf0.y), f2bf(hf0.z), f2bf(hf0.w),
                                 f2bf(hf1.x), f2bf(hf1.y), f2bf(hf1.z), f2bf(hf1.w)};
                    u16 tr[8] = {f2bf(rf0.x), f2bf(rf0.y), f2bf(rf0.z), f2bf(rf0.w),
                                 f2bf(rf1.x), f2bf(rf1.y), f2bf(rf1.z), f2bf(rf1.w)};
                    hv[q] = *(const uint4*)th;
                    rv[q] = *(const uint4*)tr;
                }
            }
#pragma unroll
            for (int q = 0; q < 4; ++q) {
                float w = wq[q];
                u32 hu[4] = {hv[q].x, hv[q].y, hv[q].z, hv[q].w};
                u32 ru[4] = {rv[q].x, rv[q].y, rv[q].z, rv[q].w};
#pragma unroll
                for (int c = 0; c < 4; ++c) {
                    acc[c * 2 + 0] += w * bf_lo(hu[c]) * bf_lo(ru[c]);
                    acc[c * 2 + 1] += w * bf_hi(hu[c]) * bf_hi(ru[c]);
                }
                wsum += w;
            }
        }

        // agg row -> swizzled LDS (first K-half)
        u32 outw[4];
#pragma unroll
        for (int c = 0; c < 4; ++c)
            outw[c] = (u32)f2bf(acc[c * 2]) | ((u32)f2bf(acc[c * 2 + 1]) << 16);
        int swm = (m & 7) << 3;
        *(uint4*)&xs[m * 512 + ((l32 * 8) ^ swm)] = *(const uint4*)outw;
        // node's own h row -> second K-half
        uint4 hrow = make_uint4(0u, 0u, 0u, 0u);
        if (valid) {
            if (BF) {
                hrow = *(const uint4*)(h_bf + (size_t)n * 256 + l32 * 8);
            } else {
                const float* hp = h + (size_t)n * 256 + l32 * 8;
                float4 f0 = *(const float4*)hp, f1 = *(const float4*)(hp + 4);
                u16 tmp[8] = {f2bf(f0.x), f2bf(f0.y), f2bf(f0.z), f2bf(f0.w),
                              f2bf(f1.x), f2bf(f1.y), f2bf(f1.z), f2bf(f1.w)};
                hrow = *(const uint4*)tmp;
            }
        }
        *(uint4*)&xs[m * 512 + ((256 + l32 * 8) ^ swm)] = hrow;
        if (l32 == 0) ws_l[m] = wsum;
    }
    __syncthreads();

    // ---- GEMM phase ----
    f32x4 acc[2][4];
#pragma unroll
    for (int f = 0; f < 2; ++f)
#pragma unroll
        for (int nf = 0; nf < 4; ++nf) acc[f][nf] = (f32x4)(0.f);

    const int swz = (l15 & 7) << 3;
#pragma unroll 4
    for (int k0 = 0; k0 < 512; k0 += 32) {
        int kk = k0 + kg * 8;
        int ksi = k0 >> 5;
        bf16x8 a[2], b[4];
#pragma unroll
        for (int f = 0; f < 2; ++f)
            a[f] = *(const bf16x8*)&xs[(f * 16 + l15) * 512 + (kk ^ swz)];
#pragma unroll
        for (int nf = 0; nf < 4; ++nf)
            b[nf] = *(const bf16x8*)(Kr + (size_t)((pt0 + nf) * 16 + ksi) * 512 + lane * 8);
#pragma unroll
        for (int f = 0; f < 2; ++f)
#pragma unroll
            for (int nf = 0; nf < 4; ++nf)
                acc[f][nf] = __builtin_amdgcn_mfma_f32_16x16x32_bf16(a[f], b[nf], acc[f][nf], 0, 0, 0);
    }

    // ---- epilogue: y = acc + c0[p] + c1[p]*ws_l[m] ----
    float b0[4], b1[4];
#pragma unroll
    for (int nf = 0; nf < 4; ++nf) {
        int p = pbase + nf * 16 + l15;
        b0[nf] = c0[p];
        b1[nf] = c1[p];
    }
#pragma unroll
    for (int f = 0; f < 2; ++f) {
#pragma unroll
        for (int r = 0; r < 4; ++r) {
            int m = f * 16 + kg * 4 + r;
            int row = m0 + m;
            if (row >= N) continue;
            float wsv = ws_l[m];
#pragma unroll
            for (int nf = 0; nf < 4; ++nf) {
                int p = pbase + nf * 16 + l15;
                dio[(size_t)row * 256 + p] = acc[f][nf][r] + b0[nf] + b1[nf] * wsv;
            }
        }
    }
}

static inline size_t align4(size_t x) { return (x + 3) & ~(size_t)3; }
static inline int imax(int a, int b) { return a > b ? a : b; }

extern "C" void kernel_launch(void* const* d_in, const int* in_sizes, int n_in,
                              void* d_out, int out_size, void* d_ws, size_t ws_size,
                              hipStream_t stream) {
    const float* h       = (const float*)d_in[0];
    const int*   ei      = (const int*)d_in[1];   // (2,E) row-major
    const int*   et      = (const int*)d_in[2];
    const float* rel_emb = (const float*)d_in[3];
    const float* msg_w   = (const float*)d_in[4];
    const float* msg_b   = (const float*)d_in[5];
    const float* upd_w   = (const float*)d_in[6];
    const float* upd_b   = (const float*)d_in[7];
    const float* gate_w  = (const float*)d_in[8];
    const float* gate_b  = (const float*)d_in[9];

    const int N = in_sizes[0] / 256;
    const int E = in_sizes[2];
    const int R = in_sizes[3] / 256;

    // workspace layout (u32 units); total+deg_src+deg_dst contiguous for memset
    u32* ws = (u32*)d_ws;
    size_t o = 0;
    u32* total    = ws + o; o += 4;
    u32* deg_src  = ws + o; o += align4((size_t)N);
    u32* deg_dst  = ws + o; o += align4((size_t)N);
    u32* offs     = ws + o; o += align4((size_t)N);
    u32* cursor   = ws + o; o += align4((size_t)N);
    float* gate   = (float*)(ws + o); o += align4((size_t)R);
    uint2* edata  = (uint2*)(ws + o); o += (size_t)2 * E;
    u16* Kcomb    = (u16*)(ws + o); o += 524288;    // 8 x 256KB fragment-packed
    float* c0     = (float*)(ws + o); o += 256;
    float* c1     = (float*)(ws + o); o += 256;
    size_t need_base = o;
    u16* h_bf     = (u16*)(ws + o); o += (size_t)N * 128;
    u16* rel_bf   = (u16*)(ws + o); o += (size_t)R * 128;
    size_t need_bf = o;

    if (ws_size < need_base * 4) return;  // insufficient scratch -> fail loudly
    const bool use_bf = (ws_size >= need_bf * 4);

    float* out = (float*)d_out;

    // zero total + degree counters (contiguous)
    hipMemsetAsync(total, 0, (4 + 2 * align4((size_t)N)) * 4, stream);

    const int nbDeg  = (E + 255) / 256;
    const int nbGate = (R + 3) / 4;
    const int gridA  = 2 * imax(nbDeg, 256 + nbGate);
    prepA_kernel<<<gridA, 256, 0, stream>>>(
        msg_w, upd_w, upd_b, msg_b, rel_emb, gate_w, gate_b, ei, E,
        deg_src, deg_dst, gate, Kcomb, c0, c1, R, nbDeg, nbGate);

    alloc_kernel<<<(N + 255) / 256, 256, 0, stream>>>(deg_dst, offs, cursor, total, N);

    const int nbFill = (E + 255) / 256;
    const int nbRel  = use_bf ? (R * 32 + 255) / 256 : 0;
    const int nbH    = use_bf ? imax(256, nbFill - nbRel) : 0;
    const int gridB  = 2 * imax(nbFill, nbH + nbRel);
    if (use_bf) {
        prepB_kernel<1><<<gridB, 256, 0, stream>>>(
            ei, et, deg_src, deg_dst, gate, cursor, edata, h, rel_emb,
            h_bf, rel_bf, E, N, R, nbFill, nbH, nbRel);
        aggemm_kernel<1><<<(N + 31) / 32, 256, 0, stream>>>(
            out, h, h_bf, rel_emb, rel_bf, Kcomb, offs, deg_dst, edata, c0, c1, N);
    } else {
        prepB_kernel<0><<<gridB, 256, 0, stream>>>(
            ei, et, deg_src, deg_dst, gate, cursor, edata, h, rel_emb,
            h_bf, rel_bf, E, N, R, nbFill, nbH, nbRel);
        aggemm_kernel<0><<<(N + 31) / 32, 256, 0, stream>>>(
            out, h, h_bf, rel_emb, rel_bf, Kcomb, offs, deg_dst, edata, c0, c1, N);
    }
}